// Round 12
// baseline (535.443 us; speedup 1.0000x reference)
//
#include <hip/hip_runtime.h>

// ---------------------------------------------------------------------------
// GraphSAGE layer — ROUND 12. Single __global__ symbol, fp32 I/O, bitmask adj.
// vs R11: (a) bit-pack prep replaces __ballot (in-thread pack of 32 k-bits
// from 8 int4 loads — no cross-lane serialization, coalesced u32 stores);
// (b) phase 1 A-tile double-buffered in LDS (2x32 KB) -> 1 barrier/iter,
// unpack overlaps MFMA. B remains direct-from-global tiled (xTt).
//
// dispatch 0 (phase 0, 9984 blocks, 9216 B LDS):
//   [0,256) cbias | [256,768) fused weights | [768,1792) x -> xTt | rest bits
// dispatch 1 (phase 1, grid (8,64), 65536 B LDS): agg = mask@x * invdeg
//   BM=128 BN=64 BK=128, mfma 32x32x16, wave-tile 64x32, A dbuf LDS
// dispatch 2 (phase 2, grid (4,128), 24576 B LDS): out = relu([x|agg]@Wt^T+cb)
// ---------------------------------------------------------------------------

using short8 = __attribute__((ext_vector_type(8))) short;   // 8 bf16 (4 VGPRs)
using f32x4  = __attribute__((ext_vector_type(4))) float;
using f32x16 = __attribute__((ext_vector_type(16))) float;  // 32x32 MFMA acc

typedef unsigned short U16;
typedef unsigned int   U32;
typedef unsigned long long U64;

__device__ __forceinline__ U16 f2bf(float f) {
  U32 u = __float_as_uint(f);
  u = (u + 0x7fffu + ((u >> 16) & 1u)) >> 16;   // RNE
  return (U16)u;
}
__device__ __forceinline__ U32 pack2bf(float a, float b) {
  return (U32)f2bf(a) | ((U32)f2bf(b) << 16);
}
// 2 adjacency bits -> 2 packed bf16 {0,1.0}
__device__ __forceinline__ U32 exp2bits(U32 w, int j) {
  U32 t2 = (w >> (2 * j)) & 3u;
  return ((t2 | (t2 << 15)) & 0x10001u) * 0x3F80u;
}
// unpack 64 adjacency bits of one row-half into a swizzled 128-elem LDS row
__device__ __forceinline__ void unpackA(U64 ab, U16* awr, int h, int rx) {
  U32 wlo = (U32)ab, whi = (U32)(ab >> 32);
  U32 o[32];
#pragma unroll
  for (int j = 0; j < 16; ++j) {
    o[j]      = exp2bits(wlo, j);
    o[16 + j] = exp2bits(whi, j);
  }
#pragma unroll
  for (int i = 0; i < 8; ++i)
    *(uint4*)(awr + (((h * 8 + i) ^ rx) * 8)) =
        make_uint4(o[4*i], o[4*i+1], o[4*i+2], o[4*i+3]);
}

__global__ __launch_bounds__(256, 2)
void GraphSAGELayer_773094114149_kernel(
    int phase,
    const float* __restrict__ x,     const int* __restrict__ adj,
    const float* __restrict__ Wself, const float* __restrict__ bself,
    const float* __restrict__ Wnb,   const float* __restrict__ bnb,
    const float* __restrict__ Wcomb, const float* __restrict__ bcomb,
    U16* __restrict__ xTt, U16* __restrict__ aggp, U64* __restrict__ bits,
    float* __restrict__ invdeg, U16* __restrict__ Wt,
    float* __restrict__ cbias, float* __restrict__ outp)
{
  extern __shared__ __align__(16) unsigned char smem[];
  const int tid = threadIdx.x;

  // =========================================================================
  // phase 0: prep  [cbias | weights | transpose->tiled | bit-pack]
  // =========================================================================
  if (phase == 0) {
    if (blockIdx.x < 256) {
      const int n0 = blockIdx.x * 2;
      float* red = (float*)smem;                // [2][256]
      float s0 = 0.f, s1 = 0.f;
#pragma unroll
      for (int jj = 0; jj < 4; ++jj) {
        int j = tid * 4 + jj;
        float bvv = (j < 512) ? bself[j] : bnb[j - 512];
        s0 += bvv * Wcomb[(size_t)j * 512 + n0];
        s1 += bvv * Wcomb[(size_t)j * 512 + n0 + 1];
      }
      red[tid] = s0; red[256 + tid] = s1;
      __syncthreads();
      for (int st = 128; st > 0; st >>= 1) {
        if (tid < st) {
          red[tid]       += red[tid + st];
          red[256 + tid] += red[256 + tid + st];
        }
        __syncthreads();
      }
      if (tid == 0) {
        cbias[n0]     = red[0]   + bcomb[n0];
        cbias[n0 + 1] = red[256] + bcomb[n0 + 1];
      }
      return;
    }
    if (blockIdx.x < 768) {
      const int b2   = blockIdx.x - 256;
      const int half = b2 >> 8;
      const int k0   = (b2 & 255) * 2;
      const float* Wsrc = half ? Wnb : Wself;
      const int woff = half * 512;
      float* wsf = (float*)smem;                // [2][512]
      {
        int idx = tid * 4;
        *(float4*)&wsf[idx] = *(const float4*)&Wsrc[(size_t)(k0 + (idx >> 9)) * 512 + (idx & 511)];
      }
      __syncthreads();
      float a00 = 0.f, a01 = 0.f, a10 = 0.f, a11 = 0.f;
#pragma unroll 8
      for (int j = 0; j < 512; ++j) {
        float wc0 = Wcomb[(size_t)(woff + j) * 512 + tid];
        float wc1 = Wcomb[(size_t)(woff + j) * 512 + tid + 256];
        float s0 = wsf[j], s1 = wsf[512 + j];
        a00 += s0 * wc0;  a01 += s0 * wc1;
        a10 += s1 * wc0;  a11 += s1 * wc1;
      }
      Wt[(size_t)tid * 1024 + woff + k0]             = f2bf(a00);
      Wt[(size_t)tid * 1024 + woff + k0 + 1]         = f2bf(a10);
      Wt[(size_t)(tid + 256) * 1024 + woff + k0]     = f2bf(a01);
      Wt[(size_t)(tid + 256) * 1024 + woff + k0 + 1] = f2bf(a11);
      return;
    }
    if (blockIdx.x < 1792) {
      // ---- x fp32 -> xTt bf16 tiled (64x64 tiles via LDS)
      const int b = blockIdx.x - 768;
      const int n0 = (b & 7) * 64;
      const int m0 = (b >> 3) * 64;
      U16* tl = (U16*)smem;                     // [64][72] (144 B rows)
      const int r  = tid >> 2;
      const int cq = (tid & 3) * 16;
      const float* src = x + (size_t)(m0 + r) * 512 + n0 + cq;
      U32 pk[8];
#pragma unroll
      for (int i = 0; i < 8; ++i) {
        float2 f = *(const float2*)(src + 2 * i);
        pk[i] = pack2bf(f.x, f.y);
      }
#pragma unroll
      for (int i = 0; i < 8; ++i) {
        tl[(cq + 2*i)     * 72 + r] = (U16)(pk[i] & 0xffffu);
        tl[(cq + 2*i + 1) * 72 + r] = (U16)(pk[i] >> 16);
      }
      __syncthreads();
      const int c2 = tid >> 2;                  // ni within tile
      const int mq = (tid & 3) * 16;            // m offset
      uint4 o0 = *(const uint4*)&tl[c2 * 72 + mq];
      uint4 o1 = *(const uint4*)&tl[c2 * 72 + mq + 8];
      const int tile  = n0 >> 6;
      const int obase = (m0 + mq) >> 3;
      U16* d = xTt + (((size_t)tile * 1024 + obase) * 64 + c2) * 8;
      *(uint4*)d         = o0;
      *(uint4*)(d + 512) = o1;                  // next k-octet
      return;
    }
    // ---- adjacency -> bitmask + degree. In-thread bit pack (no ballot):
    // thread t owns k in [32t, 32t+32) -> exactly word bits32[row][t].
    {
      const int row = blockIdx.x - 1792;
      const int* base = adj + (size_t)row * 8192 + tid * 32;
      int4 v[8];
#pragma unroll
      for (int i = 0; i < 8; ++i) v[i] = ((const int4*)base)[i];
      U32 w = 0;
#pragma unroll
      for (int i = 0; i < 8; ++i) {
        w |= (U32)(v[i].x > 0) << (4 * i);
        w |= (U32)(v[i].y > 0) << (4 * i + 1);
        w |= (U32)(v[i].z > 0) << (4 * i + 2);
        w |= (U32)(v[i].w > 0) << (4 * i + 3);
      }
      ((U32*)bits)[(size_t)row * 256 + tid] = w;

      int dsum = __popc(w);
#pragma unroll
      for (int off = 32; off > 0; off >>= 1) dsum += __shfl_down(dsum, off);
      int* sred = (int*)smem;
      if ((tid & 63) == 0) sred[tid >> 6] = dsum;
      __syncthreads();
      if (tid == 0)
        invdeg[row] = 1.0f / fmaxf((float)(sred[0] + sred[1] + sred[2] + sred[3]), 1.0f);
      return;
    }
  }

  const int lane = tid & 63;
  const int wave = tid >> 6;

  // =========================================================================
  // phase 1: agg = mask@x * invdeg. grid (8,64). BM=128 BN=64 BK=128.
  // mfma 32x32x16, waves 2x2 -> wave-tile 64x32. A: double-buffered LDS
  // (bit-unpacked, [128][128] u16 x2 = 64 KB) -> ONE barrier per iter.
  // B: register double-buffer direct from tiled global (no LDS).
  // =========================================================================
  if (phase == 1) {
    U16* Abuf0 = (U16*)smem;                    // 32 KB
    U16* Abuf1 = (U16*)(smem + 32768);          // 32 KB
    const U64* bits64 = (const U64*)bits;
    const int wr = wave & 1;
    const int wc = wave >> 1;
    const int mBase = blockIdx.y * 128;

    // A staging: thread t -> row r = t>>1, 64-bit half h = t&1
    const int r = tid >> 1, h = tid & 1;
    const U64* abase = bits64 + (size_t)(mBase + r) * 128 + h;
    const int awroff = r * 128;
    const int rx = r & 15;

    // B: per-lane base offset in the tile's xTt panel
    const U16* bbase = xTt + (size_t)blockIdx.x * 524288;   // tile*1024*64*8
    const int bni = ((wc * 32 + (lane & 31)) + (lane >> 5) * 64) * 8;

    f32x16 acc[2];
#pragma unroll
    for (int a = 0; a < 2; ++a)
#pragma unroll
      for (int i = 0; i < 16; ++i) acc[a][i] = 0.f;

    // prologue: bits(0) -> buf0; load B(0); bits(1) in flight
    U64 ab0 = abase[0];
    uint4 bv[8];
#pragma unroll
    for (int ks = 0; ks < 8; ++ks)
      bv[ks] = *(const uint4*)(bbase + bni + ks * 1024);
    unpackA(ab0, Abuf0 + awroff, h, rx);
    U64 abn = abase[2];
    __syncthreads();

    for (int it = 0; it < 64; ++it) {
      U16* curA = (it & 1) ? Abuf1 : Abuf0;
      U16* nxtA = (it & 1) ? Abuf0 : Abuf1;

      // write A(it+1) into the alternate buffer (overlaps MFMAs below)
      if (it + 1 < 64) unpackA(abn, nxtA + awroff, h, rx);

      // prefetch B(it+1) and bits(it+2)
      uint4 bn[8];
      if (it + 1 < 64) {
#pragma unroll
        for (int ks = 0; ks < 8; ++ks)
          bn[ks] = *(const uint4*)(bbase + bni + ((it + 1) * 16 + ks * 2) * 512);
        if (it + 2 < 64) abn = abase[(it + 2) * 2];
      }

      // MFMAs on current tile
#pragma unroll
      for (int ks = 0; ks < 8; ++ks) {
        const int ko = ks * 2 + (lane >> 5);    // k-octet 0..15
        short8 bf = *(short8*)&bv[ks];
#pragma unroll
        for (int tm = 0; tm < 2; ++tm) {
          int m = wr * 64 + tm * 32 + (lane & 31);
          short8 af = *(const short8*)(curA + m * 128 + ((ko ^ (m & 15)) * 8));
          acc[tm] = __builtin_amdgcn_mfma_f32_32x32x16_bf16(af, bf, acc[tm], 0, 0, 0);
        }
      }

#pragma unroll
      for (int ks = 0; ks < 8; ++ks) bv[ks] = bn[ks];
      __syncthreads();   // writes of nxtA done; reads of curA done
    }

    // epilogue: C/D map col=lane&31, row=(reg&3)+8*(reg>>2)+4*(lane>>5)
    const int col = blockIdx.x * 64 + wc * 32 + (lane & 31);
#pragma unroll
    for (int tm = 0; tm < 2; ++tm) {
      const int rbase = mBase + wr * 64 + tm * 32 + 4 * (lane >> 5);
#pragma unroll
      for (int i = 0; i < 16; ++i) {
        int row = rbase + (i & 3) + 8 * (i >> 2);
        aggp[(size_t)row * 512 + col] = f2bf(acc[tm][i] * invdeg[row]);
      }
    }
    return;
  }

  // =========================================================================
  // phase 2: out = relu([x|agg] @ Wt^T + cbias). grid (4,128). K=1024, BK=64.
  // (16x16x32 path, unchanged — known-good.)
  // =========================================================================
  {
    U16* As2 = (U16*)smem;                      // [64][64]  (128 B rows)
    U16* Bs2 = (U16*)(smem + 8192);             // [128][64] (128 B rows)
    const int quad = lane >> 4;
    const int wm = (wave & 1) * 32;
    const int wn = (wave >> 1) * 64;
    const int nBase = blockIdx.x * 128;
    const int mBase = blockIdx.y * 64;

    int amr[2], agc[2]; U16* alp[2];
#pragma unroll
    for (int i = 0; i < 2; ++i) {
      int c  = i * 256 + tid;
      amr[i] = c >> 3;
      agc[i] = c & 7;
      alp[i] = As2 + amr[i] * 64 + ((agc[i] ^ (amr[i] & 7)) * 8);
    }
    const U16* bgp[4]; U16* blp[4];
#pragma unroll
    for (int i = 0; i < 4; ++i) {
      int c  = i * 256 + tid;
      int nr = c >> 3;
      int gc = c & 7;
      bgp[i] = Wt + (size_t)(nBase + nr) * 1024 + gc * 8;
      blp[i] = Bs2 + nr * 64 + ((gc ^ (nr & 7)) * 8);
    }

    f32x4 acc[2][4];
#pragma unroll
    for (int a = 0; a < 2; ++a)
#pragma unroll
      for (int b = 0; b < 4; ++b) acc[a][b] = (f32x4){0.f, 0.f, 0.f, 0.f};

    uint4 av[2], bv[4];
#pragma unroll
    for (int i = 0; i < 2; ++i) {
      const float* ap = x + (size_t)(mBase + amr[i]) * 512 + agc[i] * 8;
      float4 f0 = *(const float4*)ap;
      float4 f1 = *(const float4*)(ap + 4);
      av[i] = make_uint4(pack2bf(f0.x,f0.y), pack2bf(f0.z,f0.w),
                         pack2bf(f1.x,f1.y), pack2bf(f1.z,f1.w));
    }
#pragma unroll
    for (int i = 0; i < 4; ++i) bv[i] = *(const uint4*)(bgp[i]);

    for (int it = 0; it < 16; ++it) {
      __syncthreads();
#pragma unroll
      for (int i = 0; i < 2; ++i) *(uint4*)alp[i] = av[i];
#pragma unroll
      for (int i = 0; i < 4; ++i) *(uint4*)blp[i] = bv[i];
      __syncthreads();

      if (it + 1 < 16) {
        const int it1 = it + 1;
        if (it1 < 8) {
#pragma unroll
          for (int i = 0; i < 2; ++i) {
            const float* ap = x + (size_t)(mBase + amr[i]) * 512 + it1 * 64 + agc[i] * 8;
            float4 f0 = *(const float4*)ap;
            float4 f1 = *(const float4*)(ap + 4);
            av[i] = make_uint4(pack2bf(f0.x,f0.y), pack2bf(f0.z,f0.w),
                               pack2bf(f1.x,f1.y), pack2bf(f1.z,f1.w));
          }
        } else {
#pragma unroll
          for (int i = 0; i < 2; ++i)
            av[i] = *(const uint4*)(aggp + (size_t)(mBase + amr[i]) * 512 +
                                    (it1 - 8) * 64 + agc[i] * 8);
        }
#pragma unroll
        for (int i = 0; i < 4; ++i) bv[i] = *(const uint4*)(bgp[i] + it1 * 64);
      }

#pragma unroll
      for (int s = 0; s < 2; ++s) {
        short8 af[2], bfr[4];
        const int g = s * 4 + quad;
#pragma unroll
        for (int tm = 0; tm < 2; ++tm) {
          int m = wm + tm * 16 + (lane & 15);
          af[tm] = *(const short8*)(As2 + m * 64 + ((g ^ (m & 7)) * 8));
        }
#pragma unroll
        for (int tn = 0; tn < 4; ++tn) {
          int n = wn + tn * 16 + (lane & 15);
          bfr[tn] = *(const short8*)(Bs2 + n * 64 + ((g ^ (n & 7)) * 8));
        }
#pragma unroll
        for (int tm = 0; tm < 2; ++tm)
#pragma unroll
          for (int tn = 0; tn < 4; ++tn)
            acc[tm][tn] = __builtin_amdgcn_mfma_f32_16x16x32_bf16(
                af[tm], bfr[tn], acc[tm][tn], 0, 0, 0);
      }
    }

    float bias[4];
#pragma unroll
    for (int tn = 0; tn < 4; ++tn)
      bias[tn] = cbias[nBase + wn + tn * 16 + (lane & 15)];

#pragma unroll
    for (int tm = 0; tm < 2; ++tm) {
      int rb = wm + tm * 16 + quad * 4;
#pragma unroll
      for (int tn = 0; tn < 4; ++tn) {
        int n = nBase + wn + tn * 16 + (lane & 15);
#pragma unroll
        for (int rr = 0; rr < 4; ++rr) {
          float v = fmaxf(acc[tm][tn][rr] + bias[tn], 0.0f);
          outp[(size_t)(mBase + rb + rr) * 512 + n] = v;
        }
      }
    }
  }
}

// ---------------------------------------------------------------------------
extern "C" void kernel_launch(void* const* d_in, const int* in_sizes, int n_in,
                              void* d_out, int out_size, void* d_ws, size_t ws_size,
                              hipStream_t stream) {
  (void)in_sizes; (void)n_in; (void)out_size; (void)ws_size;

  const float* x     = (const float*)d_in[0];
  const int*   adj   = (const int*)d_in[1];
  const float* Wself = (const float*)d_in[2];
  const float* bself = (const float*)d_in[3];
  const float* Wnb   = (const float*)d_in[4];
  const float* bnb   = (const float*)d_in[5];
  const float* Wcomb = (const float*)d_in[6];
  const float* bcomb = (const float*)d_in[7];
  float* out = (float*)d_out;

  char* ws = (char*)d_ws;
  U16*   xTt    = (U16*)(ws);                   // 8 MB  tiled bf16
  U16*   aggp   = (U16*)(ws + 8388608);         // 8 MB  [8192][512] bf16
  U64*   bits   = (U64*)(ws + 16777216);        // 8 MB  [8192][128] u64
  U16*   Wt     = (U16*)(ws + 25165824);        // 1 MB  [512][1024] bf16
  float* cbias  = (float*)(ws + 26214400);      // 2 KB
  float* invdeg = (float*)(ws + 26216448);      // 32 KB

#define ARGS(P) (P), x, adj, Wself, bself, Wnb, bnb, Wcomb, bcomb, \
                xTt, aggp, bits, invdeg, Wt, cbias, out
  GraphSAGELayer_773094114149_kernel<<<dim3(9984),   256,  9216, stream>>>(ARGS(0));
  GraphSAGELayer_773094114149_kernel<<<dim3(8, 64),  256, 65536, stream>>>(ARGS(1));
  GraphSAGELayer_773094114149_kernel<<<dim3(4, 128), 256, 24576, stream>>>(ARGS(2));
#undef ARGS
}